// Round 2
// baseline (314.787 us; speedup 1.0000x reference)
//
#include <hip/hip_runtime.h>

// Single-head causal attention, FUSED: x[512,256,384] fp32, w_qkv[384,192] fp32
//   qkv = x @ w_qkv ; out = softmax_causal(q k^T / sqrt(384)) @ v -> [512,256,64] fp32
//
// Round 6: 2-batch-per-block pipeline. Grid 256 (one occupancy round at
//   1 block/CU). Per block: [p1(b0) -> epi(b0) -> p2(b0)] then same for b1,
//   with b1's slab-0 X/W register prefetch issued at the END of p1(b0)'s
//   kc-loop so its HBM latency+drain hides under epilogue+phase2 of b0.
//   All inner structures identical to the verified round-5 kernel:
//     p1: 256x192 MFMA GEMM, BK=64, pad-72 X staging (reg cvt_pkrtz),
//         XOR-swizzled W; epi: Q*scale*log2e, K (XOR-swizzled), V^T (pad-264)
//         into LDS; p2: S^T = K.Q^T (16x16x32_f16), P = exp2 (no max-shift),
//         O^T += V^T.P (16x16x16f16); waves own query-chunks {wv,15-wv}
//         (17 key-tiles each, perfectly balanced).
// HBM: read x 201MB + write out 33.5MB = 235MB. Fill floor (harness) ~237us.

constexpr int B  = 512;
constexpr int T  = 256;
constexpr int C  = 384;
constexpr int HS = 64;
constexpr int NT = 192;
constexpr int BK = 64;
constexpr int NKC = C / BK;          // 6
constexpr int ROWP = 72;             // X staging pitch (f16): 144 B rows
constexpr int VP   = 264;            // V^T pitch: 528 B rows
constexpr float SCALE = 0.05103103630798288f;            // 1/sqrt(384)
constexpr float QSC   = SCALE * 1.4426950408889634f;     // fold log2(e) into Q

typedef _Float16 f16x8 __attribute__((ext_vector_type(8)));
typedef _Float16 f16x4 __attribute__((ext_vector_type(4)));
typedef __fp16   fp16x2_raw __attribute__((ext_vector_type(2)));
typedef float    f32x4 __attribute__((ext_vector_type(4)));

#if defined(__has_builtin)
#if __has_builtin(__builtin_amdgcn_exp2f)
#define EXP2F(v) __builtin_amdgcn_exp2f(v)
#endif
#endif
#ifndef EXP2F
#define EXP2F(v) exp2f(v)
#endif

__global__ __launch_bounds__(256)
void wt_kernel(const float* __restrict__ w, _Float16* __restrict__ wt) {
    const int idx = blockIdx.x * 256 + threadIdx.x;
    if (idx < NT * C) {
        const int n = idx / C, k = idx % C;
        wt[idx] = (_Float16)w[k * NT + n];       // wt[n][k] = w[k][n]
    }
}

__global__ __launch_bounds__(512)
void fused_kernel(const float* __restrict__ x, const _Float16* __restrict__ wt,
                  float* __restrict__ out) {
    // 36864 + 24576 + 32768 + 32768 + 33792 = 160768 B  (<= 163840)
    __shared__ __align__(16) _Float16 XL[T * ROWP];   // X slab, pad-72
    __shared__ __align__(16) _Float16 WL[NT * BK];    // W slab, XOR-swizzled linear
    __shared__ __align__(16) _Float16 QL[T * HS];     // Q * QSC, XOR-swizzled linear
    __shared__ __align__(16) _Float16 KL[T * HS];     // K, XOR-swizzled linear
    __shared__ __align__(16) _Float16 VTL[HS * VP];   // V^T, pad-264

    const int tid  = threadIdx.x;
    const int lane = tid & 63, wv = tid >> 6;
    const int l15  = lane & 15, quad = lane >> 4;
    const int wm   = wv >> 1, wn = wv & 1;           // 4 M-chunks x 2 N-chunks
    const long b0  = (long)blockIdx.x * 2;

    float4 xv[8];                                    // X prefetch regs
    uint4  wvr[3];                                   // W prefetch regs
    {
        const float* xs = x + b0 * T * C;            // b0, slab 0 prologue
#pragma unroll
        for (int i = 0; i < 8; ++i) {
            const int flat = tid + 512 * i, r = flat >> 4, seg = flat & 15;
            xv[i] = *(const float4*)(xs + r * C + seg * 4);
        }
#pragma unroll
        for (int i = 0; i < 3; ++i) {
            const int u = tid + 512 * i, n = u >> 3, sl = u & 7;
            wvr[i] = *(const uint4*)(wt + n * C + sl * 8);
        }
    }

#pragma unroll
    for (int bi = 0; bi < 2; ++bi) {
        const float* xbb = x + (b0 + bi) * T * C;

        f32x4 acc[4][6];
#pragma unroll
        for (int mi = 0; mi < 4; ++mi)
#pragma unroll
            for (int ni = 0; ni < 6; ++ni) acc[mi][ni] = (f32x4)0.f;

        // ---- Phase 1: QKV GEMM (M=256, N=192, K=384) ----
        for (int kc = 0; kc < NKC; ++kc) {
            __syncthreads();                         // prev tile fully consumed
#pragma unroll
            for (int i = 0; i < 8; ++i) {            // X: cvt + store (pad-72)
                const int flat = tid + 512 * i, r = flat >> 4, seg = flat & 15;
                union { fp16x2_raw h[2]; uint2 u; } cv;
                cv.h[0] = __builtin_amdgcn_cvt_pkrtz(xv[i].x, xv[i].y);
                cv.h[1] = __builtin_amdgcn_cvt_pkrtz(xv[i].z, xv[i].w);
                *(uint2*)&XL[r * ROWP + seg * 4] = cv.u;
            }
#pragma unroll
            for (int i = 0; i < 3; ++i) {            // W: swizzled store
                const int u = tid + 512 * i, n = u >> 3, sl = u & 7;
                *(uint4*)&WL[n * BK + ((sl ^ (n & 7)) << 3)] = wvr[i];
            }
            __syncthreads();

            // prefetch: next slab, or (bi==0, last slab) -> b1 slab 0.
            const bool last = (kc == NKC - 1);
            if (!last || bi == 0) {
                const float*    px = last ? xbb + (long)T * C : xbb + (kc + 1) * BK;
                const _Float16* pw = wt + (last ? 0 : (kc + 1) * BK);
#pragma unroll
                for (int i = 0; i < 8; ++i) {
                    const int flat = tid + 512 * i, r = flat >> 4, seg = flat & 15;
                    xv[i] = *(const float4*)(px + r * C + seg * 4);
                }
#pragma unroll
                for (int i = 0; i < 3; ++i) {
                    const int u = tid + 512 * i, n = u >> 3, sl = u & 7;
                    wvr[i] = *(const uint4*)(pw + n * C + sl * 8);
                }
            }

#pragma unroll
            for (int s = 0; s < 2; ++s) {
                const int kk = s * 32 + quad * 8;
                const int slot = kk >> 3;            // s*4 + quad
                f16x8 a[4], bf[6];
#pragma unroll
                for (int mi = 0; mi < 4; ++mi)
                    a[mi] = *(const f16x8*)&XL[(wm * 64 + mi * 16 + l15) * ROWP + kk];
#pragma unroll
                for (int ni = 0; ni < 6; ++ni) {
                    const int row = wn * 96 + ni * 16 + l15;
                    bf[ni] = *(const f16x8*)&WL[row * BK + ((slot ^ (row & 7)) << 3)];
                }
#pragma unroll
                for (int mi = 0; mi < 4; ++mi)
#pragma unroll
                    for (int ni = 0; ni < 6; ++ni)
                        acc[mi][ni] = __builtin_amdgcn_mfma_f32_16x16x32_f16(
                            a[mi], bf[ni], acc[mi][ni], 0, 0, 0);
            }
        }

        // ---- GEMM epilogue -> LDS (QL/KL swizzled scalar, VTL f16x4) ----
        // Safe vs p2(b0) when bi==1: every wave passed the kc-loop barriers,
        // which require all waves' p2 LDS reads drained (lgkmcnt before barrier).
#pragma unroll
        for (int mi = 0; mi < 4; ++mi) {
            const int t0 = wm * 64 + mi * 16 + quad * 4;
#pragma unroll
            for (int ni = 0; ni < 6; ++ni) {
                const int colbase = wn * 96 + ni * 16;
                const int col = colbase + l15;
                if (colbase < 64) {                  // Q, pre-scaled
#pragma unroll
                    for (int r = 0; r < 4; ++r) {
                        const int t = t0 + r;
                        QL[(t * HS + col) ^ ((t & 7) << 3)] =
                            (_Float16)(acc[mi][ni][r] * QSC);
                    }
                } else if (colbase < 128) {          // K
#pragma unroll
                    for (int r = 0; r < 4; ++r) {
                        const int t = t0 + r;
                        KL[(t * HS + (col - 64)) ^ ((t & 7) << 3)] =
                            (_Float16)acc[mi][ni][r];
                    }
                } else {                             // V^T [d][t]
                    f16x4 pv;
#pragma unroll
                    for (int r = 0; r < 4; ++r) pv[r] = (_Float16)acc[mi][ni][r];
                    *(f16x4*)&VTL[(col - 128) * VP + t0] = pv;
                }
            }
        }
        __syncthreads();

        // ---- Phase 2: causal attention from LDS ----
        // wave wv: chunks {wv, 15-wv} -> (wv+1)+(16-wv) = 17 key-tiles each
        float* ob = out + (b0 + bi) * T * HS;
#pragma unroll
        for (int pass = 0; pass < 2; ++pass) {
            const int ch = pass ? (15 - wv) : wv;
            const int q0 = ch * 16;
            const int qrow = q0 + l15;
            const f16x8 qf0 = *(const f16x8*)&QL[(qrow * HS + quad * 8) ^ ((qrow & 7) << 3)];
            const f16x8 qf1 = *(const f16x8*)&QL[(qrow * HS + 32 + quad * 8) ^ ((qrow & 7) << 3)];
            f32x4 o[4];
#pragma unroll
            for (int di = 0; di < 4; ++di) o[di] = (f32x4)0.f;
            float lp = 0.f;

            for (int kt = 0; kt <= ch; ++kt) {       // wave-uniform trip count
                const int k0 = kt * 16;
                const int krow = k0 + l15;
                const f16x8 ka0 = *(const f16x8*)&KL[(krow * HS + quad * 8) ^ ((krow & 7) << 3)];
                const f16x8 ka1 = *(const f16x8*)&KL[(krow * HS + 32 + quad * 8) ^ ((krow & 7) << 3)];
                f16x4 va[4];
#pragma unroll
                for (int di = 0; di < 4; ++di)
                    va[di] = *(const f16x4*)&VTL[(di * 16 + l15) * VP + k0 + quad * 4];

                // S^T tile: lane holds q = l15, keys = quad*4 + r (pre-scaled)
                f32x4 s = {0.f, 0.f, 0.f, 0.f};
                s = __builtin_amdgcn_mfma_f32_16x16x32_f16(ka0, qf0, s, 0, 0, 0);
                s = __builtin_amdgcn_mfma_f32_16x16x32_f16(ka1, qf1, s, 0, 0, 0);

                const bool dmask = (kt == ch);
                f16x4 pb; float psum = 0.f;
#pragma unroll
                for (int r = 0; r < 4; ++r) {
                    float pr = EXP2F(s[r]);          // logits bounded: no max-shift
                    pr = (dmask && (quad * 4 + r > l15)) ? 0.f : pr;
                    psum += pr;
                    pb[r] = (_Float16)pr;
                }
                lp += psum;
#pragma unroll
                for (int di = 0; di < 4; ++di)       // O^T[d][q] += V^T . P^T
                    o[di] = __builtin_amdgcn_mfma_f32_16x16x16f16(va[di], pb, o[di], 0, 0, 0);
            }

            float v = lp;                            // combine quad partials per q
            v += __shfl_xor(v, 16, 64);
            v += __shfl_xor(v, 32, 64);
            const float inv = 1.0f / v;
#pragma unroll
            for (int di = 0; di < 4; ++di) {
                float4 val;
                val.x = o[di][0] * inv; val.y = o[di][1] * inv;
                val.z = o[di][2] * inv; val.w = o[di][3] * inv;
                *(float4*)&ob[qrow * HS + di * 16 + quad * 4] = val;
            }
        }
    }
}

extern "C" void kernel_launch(void* const* d_in, const int* in_sizes, int n_in,
                              void* d_out, int out_size, void* d_ws, size_t ws_size,
                              hipStream_t stream) {
    const float* x = (const float*)d_in[0];          // [512,256,384]
    const float* w = (const float*)d_in[1];          // [384,192]
    float* out = (float*)d_out;                      // [512,256,64] fp32

    _Float16* wt = (_Float16*)d_ws;                  // [192][384] f16

    wt_kernel<<<dim3((NT * C + 255) / 256), dim3(256), 0, stream>>>(w, wt);
    fused_kernel<<<dim3(B / 2), dim3(512), 0, stream>>>(x, wt, out);
}

// Round 3
// 299.596 us; speedup vs baseline: 1.0507x; 1.0507x over previous
//
#include <hip/hip_runtime.h>

// Single-head causal attention, FUSED: x[512,256,384] fp32, w_qkv[384,192] fp32
//   qkv = x @ w_qkv ; out = softmax_causal(q k^T / sqrt(384)) @ v -> [512,256,64] fp32
//
// Round 7: barrier-free streaming GEMM. One block per batch (grid 512).
//   Phase 1: NO X/W slab staging. W^T staged ONCE per block into XOR-swizzled
//     LDS arena (147 KB); X A-fragments loaded DIRECTLY from global in MFMA
//     fragment layout (8 contiguous f32/lane, double-buffered regs,
//     issue-before-wait), cvt_pkrtz at use. Waves own DISTINCT 32-row strips
//     (2mi x 12ni acc) -> zero duplicate HBM fetches, ZERO barriers in K-loop,
//     every wave free-runs -> HBM duty ~continuous.
//   Epilogue: Q*scale*log2e, K (XOR-swizzled), V^T (pad-264) into the SAME
//     arena (aliased; barrier-protected).
//   Phase 2: verified attention: S^T = K.Q^T (16x16x32_f16), P = exp2 (no
//     max-shift), O^T += V^T.P (16x16x16f16); waves own query-chunk pairs
//     {wv, 15-wv} (17 key-tiles each, perfectly balanced).
// HBM: read x 201MB once + write out 33.5MB. Fill floor (harness) ~239us.

constexpr int B  = 512;
constexpr int T  = 256;
constexpr int C  = 384;
constexpr int HS = 64;
constexpr int NT = 192;
constexpr int VP = 264;              // V^T pitch: 528 B rows
constexpr float SCALE = 0.05103103630798288f;            // 1/sqrt(384)
constexpr float QSC   = SCALE * 1.4426950408889634f;     // fold log2(e) into Q

typedef _Float16 f16x8 __attribute__((ext_vector_type(8)));
typedef _Float16 f16x4 __attribute__((ext_vector_type(4)));
typedef __fp16   fp16x2_raw __attribute__((ext_vector_type(2)));
typedef float    f32x4 __attribute__((ext_vector_type(4)));

#if defined(__has_builtin)
#if __has_builtin(__builtin_amdgcn_exp2f)
#define EXP2F(v) __builtin_amdgcn_exp2f(v)
#endif
#endif
#ifndef EXP2F
#define EXP2F(v) exp2f(v)
#endif

__global__ __launch_bounds__(256)
void wt_kernel(const float* __restrict__ w, _Float16* __restrict__ wt) {
    const int idx = blockIdx.x * 256 + threadIdx.x;
    if (idx < NT * C) {
        const int n = idx / C, k = idx % C;
        wt[idx] = (_Float16)w[k * NT + n];       // wt[n][k] = w[k][n]
    }
}

__global__ __launch_bounds__(512)
void fused_kernel(const float* __restrict__ x, const _Float16* __restrict__ wt,
                  float* __restrict__ out) {
    // Arena: phase 1 = swizzled W^T [192][384] f16 (147456 B);
    //        phase 2 = QL(32768) + KL(32768) + VTL(33792) = 99328 B (aliased).
    __shared__ __align__(16) char arena[NT * C * 2];      // 147456 B
    _Float16* const QL  = (_Float16*)arena;
    _Float16* const KL  = (_Float16*)(arena + 32768);
    _Float16* const VTL = (_Float16*)(arena + 65536);

    const int tid  = threadIdx.x;
    const int lane = tid & 63, wv = tid >> 6;
    const int l15  = lane & 15, quad = lane >> 4;
    const int swz  = (l15 & 7) << 4;             // W row-swizzle (row&7 == l15&7)
    const int q16  = quad << 4;
    const float* xb = x + (long)blockIdx.x * T * C;

    // ---- stage W^T once: linear global read -> swizzled LDS ----
#pragma unroll
    for (int i = 0; i < 18; ++i) {               // 9216 uint4 = 512*18 exact
        const int u = tid + 512 * i;
        const int n = u / 48, sl = u - n * 48;   // 48 x 16B per 768 B row
        const uint4 wv4 = *(const uint4*)((const char*)wt + (long)u * 16);
        *(uint4*)(arena + n * 768 + ((sl * 16) ^ ((n & 7) << 4))) = wv4;
    }

    // ---- A-fragment base pointers (distinct rows per wave: wv*32 + mi*16) ----
    const float* pA0 = xb + (wv * 32 + l15) * C + quad * 8;
    const float* pA1 = xb + (wv * 32 + 16 + l15) * C + quad * 8;

    f32x4 ax[2][2][2];                           // [buf][mi][half]
    ax[0][0][0] = *(const f32x4*)(pA0 + 0);
    ax[0][0][1] = *(const f32x4*)(pA0 + 4);
    ax[0][1][0] = *(const f32x4*)(pA1 + 0);
    ax[0][1][1] = *(const f32x4*)(pA1 + 4);

    f32x4 acc[2][12];
#pragma unroll
    for (int mi = 0; mi < 2; ++mi)
#pragma unroll
        for (int ni = 0; ni < 12; ++ni) acc[mi][ni] = (f32x4)0.f;

    // per-ni W row base byte offsets (row*768; swizzle applied via col term)
    int rowb[12];
#pragma unroll
    for (int ni = 0; ni < 12; ++ni) rowb[ni] = (ni * 16 + l15) * 768;

    __syncthreads();                             // W staged

    // ---- K-loop: 12 steps of K=32, zero barriers ----
#pragma unroll
    for (int t = 0; t < 12; ++t) {
        const int cur = t & 1, nxt = cur ^ 1;
        if (t < 11) {                            // issue next step FIRST (no wait)
            ax[nxt][0][0] = *(const f32x4*)(pA0 + (t + 1) * 32);
            ax[nxt][0][1] = *(const f32x4*)(pA0 + (t + 1) * 32 + 4);
            ax[nxt][1][0] = *(const f32x4*)(pA1 + (t + 1) * 32);
            ax[nxt][1][1] = *(const f32x4*)(pA1 + (t + 1) * 32 + 4);
        }
        f16x8 af[2];                             // cvt current step (waits vmcnt)
#pragma unroll
        for (int mi = 0; mi < 2; ++mi) {
            union { fp16x2_raw h[4]; f16x8 v; } cu;
            cu.h[0] = __builtin_amdgcn_cvt_pkrtz(ax[cur][mi][0][0], ax[cur][mi][0][1]);
            cu.h[1] = __builtin_amdgcn_cvt_pkrtz(ax[cur][mi][0][2], ax[cur][mi][0][3]);
            cu.h[2] = __builtin_amdgcn_cvt_pkrtz(ax[cur][mi][1][0], ax[cur][mi][1][1]);
            cu.h[3] = __builtin_amdgcn_cvt_pkrtz(ax[cur][mi][1][2], ax[cur][mi][1][3]);
            af[mi] = cu.v;
        }
        const int col = ((t * 64) + q16) ^ swz;  // swizzled K-slice col (bytes)
#pragma unroll
        for (int ni = 0; ni < 12; ++ni) {
            const f16x8 bf = *(const f16x8*)(arena + rowb[ni] + col);
            acc[0][ni] = __builtin_amdgcn_mfma_f32_16x16x32_f16(af[0], bf, acc[0][ni], 0, 0, 0);
            acc[1][ni] = __builtin_amdgcn_mfma_f32_16x16x32_f16(af[1], bf, acc[1][ni], 0, 0, 0);
        }
    }

    __syncthreads();                             // all waves done reading W arena

    // ---- epilogue -> LDS (QL/KL swizzled scalar, VTL f16x4) ----
#pragma unroll
    for (int mi = 0; mi < 2; ++mi) {
        const int t0 = wv * 32 + mi * 16 + quad * 4;
#pragma unroll
        for (int ni = 0; ni < 12; ++ni) {
            const int colbase = ni * 16;
            const int col = colbase + l15;
            if (colbase < 64) {                  // Q, pre-scaled
#pragma unroll
                for (int r = 0; r < 4; ++r) {
                    const int tq = t0 + r;
                    QL[(tq * HS + col) ^ ((tq & 7) << 3)] =
                        (_Float16)(acc[mi][ni][r] * QSC);
                }
            } else if (colbase < 128) {          // K
#pragma unroll
                for (int r = 0; r < 4; ++r) {
                    const int tq = t0 + r;
                    KL[(tq * HS + (col - 64)) ^ ((tq & 7) << 3)] =
                        (_Float16)acc[mi][ni][r];
                }
            } else {                             // V^T [d][t]
                f16x4 pv;
#pragma unroll
                for (int r = 0; r < 4; ++r) pv[r] = (_Float16)acc[mi][ni][r];
                *(f16x4*)&VTL[(col - 128) * VP + t0] = pv;
            }
        }
    }
    __syncthreads();

    // ---- Phase 2: causal attention from LDS ----
    // wave wv: chunks {wv, 15-wv} -> (wv+1)+(16-wv) = 17 key-tiles each
    float* ob = out + (long)blockIdx.x * T * HS;
#pragma unroll
    for (int pass = 0; pass < 2; ++pass) {
        const int ch = pass ? (15 - wv) : wv;
        const int q0 = ch * 16;
        const int qrow = q0 + l15;
        const f16x8 qf0 = *(const f16x8*)&QL[(qrow * HS + quad * 8) ^ ((qrow & 7) << 3)];
        const f16x8 qf1 = *(const f16x8*)&QL[(qrow * HS + 32 + quad * 8) ^ ((qrow & 7) << 3)];
        f32x4 o[4];
#pragma unroll
        for (int di = 0; di < 4; ++di) o[di] = (f32x4)0.f;
        float lp = 0.f;

        for (int kt = 0; kt <= ch; ++kt) {       // wave-uniform trip count
            const int k0 = kt * 16;
            const int krow = k0 + l15;
            const f16x8 ka0 = *(const f16x8*)&KL[(krow * HS + quad * 8) ^ ((krow & 7) << 3)];
            const f16x8 ka1 = *(const f16x8*)&KL[(krow * HS + 32 + quad * 8) ^ ((krow & 7) << 3)];
            f16x4 va[4];
#pragma unroll
            for (int di = 0; di < 4; ++di)
                va[di] = *(const f16x4*)&VTL[(di * 16 + l15) * VP + k0 + quad * 4];

            // S^T tile: lane holds q = l15, keys = quad*4 + r (pre-scaled)
            f32x4 s = {0.f, 0.f, 0.f, 0.f};
            s = __builtin_amdgcn_mfma_f32_16x16x32_f16(ka0, qf0, s, 0, 0, 0);
            s = __builtin_amdgcn_mfma_f32_16x16x32_f16(ka1, qf1, s, 0, 0, 0);

            const bool dmask = (kt == ch);
            f16x4 pb; float psum = 0.f;
#pragma unroll
            for (int r = 0; r < 4; ++r) {
                float pr = EXP2F(s[r]);          // logits bounded: no max-shift
                pr = (dmask && (quad * 4 + r > l15)) ? 0.f : pr;
                psum += pr;
                pb[r] = (_Float16)pr;
            }
            lp += psum;
#pragma unroll
            for (int di = 0; di < 4; ++di)       // O^T[d][q] += V^T . P^T
                o[di] = __builtin_amdgcn_mfma_f32_16x16x16f16(va[di], pb, o[di], 0, 0, 0);
        }

        float v = lp;                            // combine quad partials per q
        v += __shfl_xor(v, 16, 64);
        v += __shfl_xor(v, 32, 64);
        const float inv = 1.0f / v;
#pragma unroll
        for (int di = 0; di < 4; ++di) {
            float4 val;
            val.x = o[di][0] * inv; val.y = o[di][1] * inv;
            val.z = o[di][2] * inv; val.w = o[di][3] * inv;
            *(float4*)&ob[qrow * HS + di * 16 + quad * 4] = val;
        }
    }
}

extern "C" void kernel_launch(void* const* d_in, const int* in_sizes, int n_in,
                              void* d_out, int out_size, void* d_ws, size_t ws_size,
                              hipStream_t stream) {
    const float* x = (const float*)d_in[0];      // [512,256,384]
    const float* w = (const float*)d_in[1];      // [384,192]
    float* out = (float*)d_out;                  // [512,256,64] fp32

    _Float16* wt = (_Float16*)d_ws;              // [192][384] f16

    wt_kernel<<<dim3((NT * C + 255) / 256), dim3(256), 0, stream>>>(w, wt);
    fused_kernel<<<dim3(B), dim3(512), 0, stream>>>(x, wt, out);
}